// Round 2
// baseline (493.104 us; speedup 1.0000x reference)
//
#include <hip/hip_runtime.h>

// SparseProjection: out[b,k] = dot(weight[indices[b,k]], inp[b]) + bias[indices[b,k]]
// B=4096, K=128, D=512, V=128000, fp32, sparse=1 always.
//
// Round-2 strategy: invert the gather. Counting-sort the 512K (b,k) pairs by
// vocab index v (histogram -> atomic bucket alloc -> scatter), then one wave
// per vocab row streams the weight row from HBM EXACTLY ONCE (sequential, vs
// round-1's 2.07x random re-fetch at 2.9 TB/s) and computes all ~4.1 dots for
// that row against L2/L3-resident inp rows (8 MB table).

constexpr int Bc = 4096;
constexpr int Kc = 128;
constexpr int Dc = 512;
constexpr int Vc = 128000;
constexpr int NB = Bc * Kc;          // 524288 pairs

// ---- workspace layout (bytes) ----
// [0, 512000)        hist   : u32[V]
// [512000, 512256)   cursor : u32 (+pad)
// [512256, 1024256)  start  : u32[V]
// [1024256, 1536256) cur    : u32[V]
// [1536256, 3633408) pairs  : u32[NB]
constexpr size_t WS_HIST   = 0;
constexpr size_t WS_CURSOR = 512000;
constexpr size_t WS_START  = 512256;
constexpr size_t WS_CUR    = 1024256;
constexpr size_t WS_PAIRS  = 1536256;
constexpr size_t WS_NEED   = WS_PAIRS + (size_t)NB * 4;

__global__ __launch_bounds__(256) void hist_kernel(
    const int* __restrict__ indices, unsigned* __restrict__ hist)
{
    int i = blockIdx.x * 256 + threadIdx.x;
    if (i < NB) atomicAdd(&hist[indices[i]], 1u);
}

__global__ __launch_bounds__(256) void alloc_kernel(
    const unsigned* __restrict__ hist, unsigned* __restrict__ start,
    unsigned* __restrict__ cur, unsigned* __restrict__ cursor)
{
    int v = blockIdx.x * 256 + threadIdx.x;
    if (v < Vc) {
        unsigned c = hist[v];
        unsigned s = c ? atomicAdd(cursor, c) : 0u;
        start[v] = s;
        cur[v]   = s;
    }
}

__global__ __launch_bounds__(256) void scatter_kernel(
    const int* __restrict__ indices, unsigned* __restrict__ cur,
    unsigned* __restrict__ pairs)
{
    int i = blockIdx.x * 256 + threadIdx.x;
    if (i < NB) {
        int v = indices[i];
        unsigned pos = atomicAdd(&cur[v], 1u);
        pairs[pos] = (unsigned)i;      // i = b*128 + k
    }
}

__global__ __launch_bounds__(256) void compute_kernel(
    const float* __restrict__ inp,     // [B, D]
    const float* __restrict__ weight,  // [V, D]
    const float* __restrict__ bias,    // [V]
    const unsigned* __restrict__ hist,
    const unsigned* __restrict__ start,
    const unsigned* __restrict__ pairs,
    float* __restrict__ out)           // [B, K]
{
    const int wave = threadIdx.x >> 6;
    const int lane = threadIdx.x & 63;
    const int v    = blockIdx.x * 4 + wave;        // one wave per vocab row
    // V = 128000 = 32000 blocks * 4 waves exactly.

    const unsigned cnt = hist[v];                  // wave-uniform
    if (cnt == 0) return;
    const unsigned st = start[v];

    // Stream this weight row once: 64 lanes x 8 floats = 2 KB, sequential in v.
    const float4* wrow = (const float4*)(weight + (size_t)v * Dc);
    const float4 w0 = wrow[lane];
    const float4 w1 = wrow[64 + lane];
    const float  bv = bias[v];

    for (unsigned e = 0; e < cnt; ++e) {
        const unsigned i = pairs[st + e];          // wave-uniform
        const unsigned b = i >> 7;
        const float4* arow = (const float4*)(inp + (size_t)b * Dc);
        const float4 a0 = arow[lane];              // L2/L3-resident (8 MB table)
        const float4 a1 = arow[64 + lane];

        float s = a0.x * w0.x + a0.y * w0.y + a0.z * w0.z + a0.w * w0.w
                + a1.x * w1.x + a1.y * w1.y + a1.z * w1.z + a1.w * w1.w;

        #pragma unroll
        for (int off = 32; off > 0; off >>= 1)
            s += __shfl_xor(s, off, 64);

        if (lane == 0) out[i] = s + bv;
    }
}

// ---- round-1 fallback (if workspace too small) ----
__global__ __launch_bounds__(256) void fallback_kernel(
    const float* __restrict__ inp, const int* __restrict__ indices,
    const float* __restrict__ weight, const float* __restrict__ bias,
    float* __restrict__ out)
{
    const int b = blockIdx.x, lane = threadIdx.x & 63, wave = threadIdx.x >> 6;
    const float4* inp_row = (const float4*)(inp + (size_t)b * Dc);
    const float4 a0 = inp_row[lane];
    const float4 a1 = inp_row[64 + lane];
    const int* idx_base = indices + (size_t)b * Kc;
    float* out_base = out + (size_t)b * Kc;
    #pragma unroll 4
    for (int i = 0; i < 32; ++i) {
        const int k = wave * 32 + i;
        const int idx = idx_base[k];
        const float4* wrow = (const float4*)(weight + (size_t)idx * Dc);
        const float4 w0 = wrow[lane];
        const float4 w1 = wrow[64 + lane];
        float s = a0.x * w0.x + a0.y * w0.y + a0.z * w0.z + a0.w * w0.w
                + a1.x * w1.x + a1.y * w1.y + a1.z * w1.z + a1.w * w1.w;
        #pragma unroll
        for (int off = 32; off > 0; off >>= 1) s += __shfl_xor(s, off, 64);
        if (lane == 0) out_base[k] = s + bias[idx];
    }
}

extern "C" void kernel_launch(void* const* d_in, const int* in_sizes, int n_in,
                              void* d_out, int out_size, void* d_ws, size_t ws_size,
                              hipStream_t stream) {
    const float* inp     = (const float*)d_in[0];   // [4096, 512]
    const int*   indices = (const int*)  d_in[1];   // [4096, 128]
    const float* weight  = (const float*)d_in[3];   // [128000, 512]
    const float* bias    = (const float*)d_in[4];   // [128000]
    float*       out     = (float*)d_out;           // [4096, 128]

    if (ws_size < WS_NEED) {   // safety net: round-1 kernel (191 us)
        fallback_kernel<<<Bc, 256, 0, stream>>>(inp, indices, weight, bias, out);
        return;
    }

    char* ws = (char*)d_ws;
    unsigned* hist   = (unsigned*)(ws + WS_HIST);
    unsigned* cursor = (unsigned*)(ws + WS_CURSOR);
    unsigned* start  = (unsigned*)(ws + WS_START);
    unsigned* cur    = (unsigned*)(ws + WS_CUR);
    unsigned* pairs  = (unsigned*)(ws + WS_PAIRS);

    // zero hist + cursor in one contiguous memset (graph-capturable)
    hipMemsetAsync(ws, 0, WS_START, stream);

    hist_kernel   <<<(NB + 255) / 256, 256, 0, stream>>>(indices, hist);
    alloc_kernel  <<<(Vc + 255) / 256, 256, 0, stream>>>(hist, start, cur, cursor);
    scatter_kernel<<<(NB + 255) / 256, 256, 0, stream>>>(indices, cur, pairs);
    compute_kernel<<<Vc / 4,            256, 0, stream>>>(inp, weight, bias,
                                                          hist, start, pairs, out);
}

// Round 3
// 450.169 us; speedup vs baseline: 1.0954x; 1.0954x over previous
//
#include <hip/hip_runtime.h>
#include <hip/hip_fp16.h>

// SparseProjection: out[b,k] = dot(weight[indices[b,k]], inp[b]) + bias[indices[b,k]]
// B=4096, K=128, D=512, V=128000, fp32, sparse=1 always.
//
// Round-3: counting-sort pairs by vocab index (weight streamed from HBM exactly
// once, held in registers per wave), and convert inp to fp16 (4 MB table ==
// one XCD L2) so the 512K random row-gathers halve in bytes and mostly hit L2.
// Round-2 evidence: 1.26 GB through the L2-miss path at ~8 TB/s was the limiter.

constexpr int Bc = 4096;
constexpr int Kc = 128;
constexpr int Dc = 512;
constexpr int Vc = 128000;
constexpr int NB = Bc * Kc;          // 524288 pairs

// ---- workspace layout (bytes) ----
constexpr size_t WS_HIST   = 0;                              // u32[V]
constexpr size_t WS_CURSOR = 512000;                         // u32
constexpr size_t WS_START  = 512256;                         // u32[V]
constexpr size_t WS_CUR    = 1024256;                        // u32[V]
constexpr size_t WS_PAIRS  = 1536256;                        // u32[NB]
constexpr size_t WS_INPH   = WS_PAIRS + (size_t)NB * 4;      // fp16[B*D] = 4 MB
constexpr size_t WS_NEED   = WS_INPH + (size_t)Bc * Dc * 2;

__global__ __launch_bounds__(256) void hist_kernel(
    const int* __restrict__ indices, unsigned* __restrict__ hist)
{
    int i = blockIdx.x * 256 + threadIdx.x;
    if (i < NB) atomicAdd(&hist[indices[i]], 1u);
}

__global__ __launch_bounds__(256) void alloc_kernel(
    const unsigned* __restrict__ hist, unsigned* __restrict__ start,
    unsigned* __restrict__ cur, unsigned* __restrict__ cursor)
{
    int v = blockIdx.x * 256 + threadIdx.x;
    if (v < Vc) {
        unsigned c = hist[v];
        unsigned s = c ? atomicAdd(cursor, c) : 0u;
        start[v] = s;
        cur[v]   = s;
    }
}

__global__ __launch_bounds__(256) void scatter_kernel(
    const int* __restrict__ indices, unsigned* __restrict__ cur,
    unsigned* __restrict__ pairs)
{
    int i = blockIdx.x * 256 + threadIdx.x;
    if (i < NB) {
        unsigned pos = atomicAdd(&cur[indices[i]], 1u);
        pairs[pos] = (unsigned)i;      // i = b*128 + k
    }
}

// fp32 -> fp16 (RNE), 4 elements/thread, 8B packed store.
__global__ __launch_bounds__(256) void convert_kernel(
    const float* __restrict__ inp, __half* __restrict__ inph)
{
    int i = blockIdx.x * 256 + threadIdx.x;            // one float4
    float4 v = ((const float4*)inp)[i];
    union { __half2 h[2]; uint2 u; } cv;
    cv.h[0] = __floats2half2_rn(v.x, v.y);
    cv.h[1] = __floats2half2_rn(v.z, v.w);
    ((uint2*)inph)[i] = cv.u;
}

__device__ __forceinline__ float2 h2f(unsigned u) {
    union { unsigned u; __half2 h; } c; c.u = u;
    return __half22float2(c.h);
}

__device__ __forceinline__ float dot8(const float4& w0, const float4& w1, const uint4& p) {
    float2 f0 = h2f(p.x), f1 = h2f(p.y), f2 = h2f(p.z), f3 = h2f(p.w);
    return w0.x * f0.x + w0.y * f0.y + w0.z * f1.x + w0.w * f1.y
         + w1.x * f2.x + w1.y * f2.y + w1.z * f3.x + w1.w * f3.y;
}

__global__ __launch_bounds__(256) void compute_kernel(
    const __half* __restrict__ inph,   // [B, D] fp16
    const float*  __restrict__ weight, // [V, D] fp32
    const float*  __restrict__ bias,   // [V]
    const unsigned* __restrict__ hist,
    const unsigned* __restrict__ start,
    const unsigned* __restrict__ pairs,
    float* __restrict__ out)           // [B, K]
{
    const int wave = threadIdx.x >> 6;
    const int lane = threadIdx.x & 63;
    const int v    = blockIdx.x * 4 + wave;   // V = 32000 blocks * 4 waves exactly

    const unsigned cnt = hist[v];             // wave-uniform
    if (cnt == 0) return;
    const unsigned st = start[v];

    // Weight row in registers: lane l holds elements [8l, 8l+8) to match the
    // fp16 row packing (one uint4 per lane covers the whole 1 KB fp16 row).
    const float4* wrow = (const float4*)(weight + (size_t)v * Dc);
    const float4 w0 = wrow[2 * lane];
    const float4 w1 = wrow[2 * lane + 1];
    const float  bv = bias[v];

    unsigned e = 0;
    for (; e + 2 <= cnt; e += 2) {            // 2 pairs in flight for ILP
        const unsigned i0 = pairs[st + e];
        const unsigned i1 = pairs[st + e + 1];
        const uint4 p0 = ((const uint4*)(inph + (size_t)(i0 >> 7) * Dc))[lane];
        const uint4 p1 = ((const uint4*)(inph + (size_t)(i1 >> 7) * Dc))[lane];
        float s0 = dot8(w0, w1, p0);
        float s1 = dot8(w0, w1, p1);
        #pragma unroll
        for (int off = 32; off > 0; off >>= 1) {
            s0 += __shfl_xor(s0, off, 64);
            s1 += __shfl_xor(s1, off, 64);
        }
        if (lane == 0) { out[i0] = s0 + bv; out[i1] = s1 + bv; }
    }
    if (e < cnt) {
        const unsigned i0 = pairs[st + e];
        const uint4 p0 = ((const uint4*)(inph + (size_t)(i0 >> 7) * Dc))[lane];
        float s0 = dot8(w0, w1, p0);
        #pragma unroll
        for (int off = 32; off > 0; off >>= 1) s0 += __shfl_xor(s0, off, 64);
        if (lane == 0) out[i0] = s0 + bv;
    }
}

// ---- round-1 fallback (if workspace too small) ----
__global__ __launch_bounds__(256) void fallback_kernel(
    const float* __restrict__ inp, const int* __restrict__ indices,
    const float* __restrict__ weight, const float* __restrict__ bias,
    float* __restrict__ out)
{
    const int b = blockIdx.x, lane = threadIdx.x & 63, wave = threadIdx.x >> 6;
    const float4* inp_row = (const float4*)(inp + (size_t)b * Dc);
    const float4 a0 = inp_row[lane];
    const float4 a1 = inp_row[64 + lane];
    const int* idx_base = indices + (size_t)b * Kc;
    float* out_base = out + (size_t)b * Kc;
    #pragma unroll 4
    for (int i = 0; i < 32; ++i) {
        const int k = wave * 32 + i;
        const int idx = idx_base[k];
        const float4* wrow = (const float4*)(weight + (size_t)idx * Dc);
        const float4 w0 = wrow[lane];
        const float4 w1 = wrow[64 + lane];
        float s = a0.x * w0.x + a0.y * w0.y + a0.z * w0.z + a0.w * w0.w
                + a1.x * w1.x + a1.y * w1.y + a1.z * w1.z + a1.w * w1.w;
        #pragma unroll
        for (int off = 32; off > 0; off >>= 1) s += __shfl_xor(s, off, 64);
        if (lane == 0) out_base[k] = s + bias[idx];
    }
}

extern "C" void kernel_launch(void* const* d_in, const int* in_sizes, int n_in,
                              void* d_out, int out_size, void* d_ws, size_t ws_size,
                              hipStream_t stream) {
    const float* inp     = (const float*)d_in[0];   // [4096, 512]
    const int*   indices = (const int*)  d_in[1];   // [4096, 128]
    const float* weight  = (const float*)d_in[3];   // [128000, 512]
    const float* bias    = (const float*)d_in[4];   // [128000]
    float*       out     = (float*)d_out;           // [4096, 128]

    if (ws_size < WS_NEED) {   // safety net: round-1 kernel (191 us)
        fallback_kernel<<<Bc, 256, 0, stream>>>(inp, indices, weight, bias, out);
        return;
    }

    char* ws = (char*)d_ws;
    unsigned* hist   = (unsigned*)(ws + WS_HIST);
    unsigned* cursor = (unsigned*)(ws + WS_CURSOR);
    unsigned* start  = (unsigned*)(ws + WS_START);
    unsigned* cur    = (unsigned*)(ws + WS_CUR);
    unsigned* pairs  = (unsigned*)(ws + WS_PAIRS);
    __half*   inph   = (__half*)  (ws + WS_INPH);

    hipMemsetAsync(ws, 0, WS_START, stream);  // hist + cursor

    convert_kernel<<<(Bc * Dc / 4) / 256, 256, 0, stream>>>(inp, inph);
    hist_kernel   <<<(NB + 255) / 256, 256, 0, stream>>>(indices, hist);
    alloc_kernel  <<<(Vc + 255) / 256, 256, 0, stream>>>(hist, start, cur, cursor);
    scatter_kernel<<<(NB + 255) / 256, 256, 0, stream>>>(indices, cur, pairs);
    compute_kernel<<<Vc / 4,            256, 0, stream>>>(inph, weight, bias,
                                                          hist, start, pairs, out);
}